// Round 3
// baseline (419.499 us; speedup 1.0000x reference)
//
#include <hip/hip_runtime.h>
#include <hip/hip_bf16.h>

#define NROWS 12288
#define NDIM  128
#define HID   16

#define JCHUNK 512
#define NCHUNK (NROWS / JCHUNK)   // 24
#define RPB    256                // rows per agg block

// Module-level scratch: avoids any dependence on ws_size.
// Fully (re)written on every kernel_launch call, so graph replay is safe.
__device__ float g_h[NROWS * HID];     // MLP output h
__device__ float g_acc[NROWS * 17];    // [sum_j p*h_j (16), sum_j p (1)] per row

// ---------------------------------------------------------------------------
// Kernel Z: zero the accumulator buffer (replaces hipMemsetAsync).
// ---------------------------------------------------------------------------
__global__ __launch_bounds__(256) void zero_acc_kernel() {
    const int i = blockIdx.x * 256 + threadIdx.x;
    if (i < NROWS * 17) g_acc[i] = 0.0f;
}

// ---------------------------------------------------------------------------
// Kernel A: h = ((x@W1+b1)@W2+b2)@W3+b3   [NROWS,16] fp32
// ---------------------------------------------------------------------------
__global__ __launch_bounds__(256) void mlp_kernel(
    const float* __restrict__ x,
    const float* __restrict__ W1, const float* __restrict__ b1,
    const float* __restrict__ W2, const float* __restrict__ b2,
    const float* __restrict__ W3, const float* __restrict__ b3)
{
    __shared__ float sW1[NDIM * HID];       // 8 KB
    __shared__ float sW2[HID * HID];
    __shared__ float sW3[HID * HID];
    __shared__ float sb[3 * HID];

    const int t = threadIdx.x;
    for (int i = t; i < NDIM * HID; i += 256) sW1[i] = W1[i];
    if (t < HID * HID) { sW2[t] = W2[t]; sW3[t] = W3[t]; }
    if (t < HID) { sb[t] = b1[t]; sb[HID + t] = b2[t]; sb[2 * HID + t] = b3[t]; }
    __syncthreads();

    const int row = blockIdx.x * 256 + t;
    if (row >= NROWS) return;

    // layer 1: 128 -> 16
    float a1[HID];
    #pragma unroll
    for (int c = 0; c < HID; ++c) a1[c] = sb[c];
    const float4* xr = reinterpret_cast<const float4*>(x + (size_t)row * NDIM);
    #pragma unroll 8
    for (int k4 = 0; k4 < NDIM / 4; ++k4) {
        float4 v = xr[k4];
        const float* w0 = &sW1[(k4 * 4 + 0) * HID];
        const float* w1 = &sW1[(k4 * 4 + 1) * HID];
        const float* w2 = &sW1[(k4 * 4 + 2) * HID];
        const float* w3 = &sW1[(k4 * 4 + 3) * HID];
        #pragma unroll
        for (int c = 0; c < HID; ++c)
            a1[c] += v.x * w0[c] + v.y * w1[c] + v.z * w2[c] + v.w * w3[c];
    }

    // layer 2: 16 -> 16
    float a2[HID];
    #pragma unroll
    for (int c = 0; c < HID; ++c) a2[c] = sb[HID + c];
    #pragma unroll
    for (int k = 0; k < HID; ++k) {
        const float hk = a1[k];
        #pragma unroll
        for (int c = 0; c < HID; ++c) a2[c] += hk * sW2[k * HID + c];
    }

    // layer 3: 16 -> 16
    float a3[HID];
    #pragma unroll
    for (int c = 0; c < HID; ++c) a3[c] = sb[2 * HID + c];
    #pragma unroll
    for (int k = 0; k < HID; ++k) {
        const float hk = a2[k];
        #pragma unroll
        for (int c = 0; c < HID; ++c) a3[c] += hk * sW3[k * HID + c];
    }

    float4* hr = reinterpret_cast<float4*>(g_h + (size_t)row * HID);
    hr[0] = make_float4(a3[0],  a3[1],  a3[2],  a3[3]);
    hr[1] = make_float4(a3[4],  a3[5],  a3[6],  a3[7]);
    hr[2] = make_float4(a3[8],  a3[9],  a3[10], a3[11]);
    hr[3] = make_float4(a3[12], a3[13], a3[14], a3[15]);
}

// ---------------------------------------------------------------------------
// Kernel B: streaming masked-softmax aggregation partials.
// Grid: (NROWS/RPB, NCHUNK). Each block stages a JCHUNK x 16 tile of h in LDS;
// each thread owns one row i and accumulates  sum_j exp(h_i.h_j) * [h_j, 1]
// over the block's j-chunk (no max subtraction: |logits| < ~1, fp32-safe;
// diagonal guarantees denominator >= 1). Partials atomicAdd into g_acc.
// ---------------------------------------------------------------------------
__global__ __launch_bounds__(256) void agg_kernel()
{
    __shared__ float hj[JCHUNK * HID];      // 32 KB

    const int t  = threadIdx.x;
    const int j0 = blockIdx.y * JCHUNK;

    // stage j-chunk tile (coalesced float4)
    const float4* src = reinterpret_cast<const float4*>(g_h + (size_t)j0 * HID);
    float4* dst = reinterpret_cast<float4*>(hj);
    #pragma unroll
    for (int i = 0; i < (JCHUNK * HID / 4) / 256; ++i)
        dst[t + i * 256] = src[t + i * 256];
    __syncthreads();

    const int row = blockIdx.x * RPB + t;

    // own row in registers
    float hi[HID];
    const float4* hr = reinterpret_cast<const float4*>(g_h + (size_t)row * HID);
    {
        float4 a = hr[0], b = hr[1], c = hr[2], d = hr[3];
        hi[0]=a.x; hi[1]=a.y; hi[2]=a.z; hi[3]=a.w;
        hi[4]=b.x; hi[5]=b.y; hi[6]=b.z; hi[7]=b.w;
        hi[8]=c.x; hi[9]=c.y; hi[10]=c.z; hi[11]=c.w;
        hi[12]=d.x; hi[13]=d.y; hi[14]=d.z; hi[15]=d.w;
    }

    float acc[HID];
    #pragma unroll
    for (int c = 0; c < HID; ++c) acc[c] = 0.0f;
    float s = 0.0f;

    #pragma unroll 2
    for (int j = 0; j < JCHUNK; ++j) {
        const float4* hp = reinterpret_cast<const float4*>(&hj[j * HID]);
        float4 v0 = hp[0], v1 = hp[1], v2 = hp[2], v3 = hp[3];  // wave-uniform -> LDS broadcast
        float hv[HID];
        hv[0]=v0.x; hv[1]=v0.y; hv[2]=v0.z; hv[3]=v0.w;
        hv[4]=v1.x; hv[5]=v1.y; hv[6]=v1.z; hv[7]=v1.w;
        hv[8]=v2.x; hv[9]=v2.y; hv[10]=v2.z; hv[11]=v2.w;
        hv[12]=v3.x; hv[13]=v3.y; hv[14]=v3.z; hv[15]=v3.w;

        float dot = 0.0f;
        #pragma unroll
        for (int k = 0; k < HID; ++k) dot += hi[k] * hv[k];

        const float p = (dot > 0.0f) ? __expf(dot) : 0.0f;  // mask == strict >0
        s += p;
        #pragma unroll
        for (int k = 0; k < HID; ++k) acc[k] += p * hv[k];
    }

    float* outp = g_acc + (size_t)row * 17;
    #pragma unroll
    for (int k = 0; k < HID; ++k) atomicAdd(outp + k, acc[k]);
    atomicAdd(outp + 16, s);
}

// ---------------------------------------------------------------------------
// Kernel C: out = log_softmax(acc / sum) per row
// ---------------------------------------------------------------------------
__global__ __launch_bounds__(256) void finalize_kernel(float* __restrict__ out)
{
    const int row = blockIdx.x * 256 + threadIdx.x;
    if (row >= NROWS) return;
    const float* a = g_acc + (size_t)row * 17;
    const float inv = 1.0f / a[16];
    float o[HID];
    float m = -3.0e38f;
    #pragma unroll
    for (int c = 0; c < HID; ++c) { o[c] = a[c] * inv; m = fmaxf(m, o[c]); }
    float sum = 0.0f;
    #pragma unroll
    for (int c = 0; c < HID; ++c) sum += __expf(o[c] - m);
    const float lse = m + __logf(sum);
    float4* op = reinterpret_cast<float4*>(out + (size_t)row * HID);
    op[0] = make_float4(o[0]-lse,  o[1]-lse,  o[2]-lse,  o[3]-lse);
    op[1] = make_float4(o[4]-lse,  o[5]-lse,  o[6]-lse,  o[7]-lse);
    op[2] = make_float4(o[8]-lse,  o[9]-lse,  o[10]-lse, o[11]-lse);
    op[3] = make_float4(o[12]-lse, o[13]-lse, o[14]-lse, o[15]-lse);
}

// ---------------------------------------------------------------------------
extern "C" void kernel_launch(void* const* d_in, const int* in_sizes, int n_in,
                              void* d_out, int out_size, void* d_ws, size_t ws_size,
                              hipStream_t stream) {
    const float* x  = (const float*)d_in[0];
    const float* W1 = (const float*)d_in[1];
    const float* b1 = (const float*)d_in[2];
    const float* W2 = (const float*)d_in[3];
    const float* b2 = (const float*)d_in[4];
    const float* W3 = (const float*)d_in[5];
    const float* b3 = (const float*)d_in[6];
    float* out = (float*)d_out;

    zero_acc_kernel<<<(NROWS * 17 + 255) / 256, 256, 0, stream>>>();
    mlp_kernel<<<NROWS / 256, 256, 0, stream>>>(x, W1, b1, W2, b2, W3, b3);
    agg_kernel<<<dim3(NROWS / RPB, NCHUNK), 256, 0, stream>>>();
    finalize_kernel<<<NROWS / 256, 256, 0, stream>>>(out);
}

// Round 4
// 135.120 us; speedup vs baseline: 3.1046x; 3.1046x over previous
//
#include <hip/hip_runtime.h>
#include <hip/hip_bf16.h>

#define NROWS 12288
#define NDIM  128
#define HID   16

#define NJC    8                 // j-chunks (partials)
#define JSPAN  (NROWS / NJC)     // 1536
#define JSTEPS (JSPAN / 32)      // 48

typedef float f32x16 __attribute__((ext_vector_type(16)));
typedef short s16x8  __attribute__((ext_vector_type(8)));

// Module-level scratch (BSS): fully rewritten every call; no d_ws dependence.
__device__ __align__(16) ushort g_hb [NROWS * HID];   // bf16 H
__device__ __align__(16) ushort g_hbs[NROWS * HID];   // bf16 (H * log2e)  (QK^T j-side)
__device__ __align__(16) ushort g_hbT[HID * NROWS];   // bf16 H^T          (PV B-side)
__device__ float g_pout[(size_t)NJC * NROWS * 16];    // PV partials
__device__ float g_pden[(size_t)NJC * NROWS];         // denom partials

__device__ __forceinline__ ushort f2bf(float f) {     // RNE f32->bf16
    union { float f; unsigned u; } v; v.f = f;
    unsigned r = v.u + 0x7fffu + ((v.u >> 16) & 1u);
    return (ushort)(r >> 16);
}

#if __has_builtin(__builtin_amdgcn_exp2f)
#define EXP2(x) __builtin_amdgcn_exp2f(x)
#else
#define EXP2(x) exp2f(x)
#endif

// ---------------------------------------------------------------------------
// Kernel A: MLP -> bf16 H, bf16 H*log2e, bf16 H^T
// ---------------------------------------------------------------------------
__global__ __launch_bounds__(256) void mlp_kernel(
    const float* __restrict__ x,
    const float* __restrict__ W1, const float* __restrict__ b1,
    const float* __restrict__ W2, const float* __restrict__ b2,
    const float* __restrict__ W3, const float* __restrict__ b3)
{
    __shared__ float sW1[NDIM * HID];
    __shared__ float sW2[HID * HID];
    __shared__ float sW3[HID * HID];
    __shared__ float sb[3 * HID];

    const int t = threadIdx.x;
    for (int i = t; i < NDIM * HID; i += 256) sW1[i] = W1[i];
    if (t < HID * HID) { sW2[t] = W2[t]; sW3[t] = W3[t]; }
    if (t < HID) { sb[t] = b1[t]; sb[HID + t] = b2[t]; sb[2 * HID + t] = b3[t]; }
    __syncthreads();

    const int row = blockIdx.x * 256 + t;
    if (row >= NROWS) return;

    float a1[HID];
    #pragma unroll
    for (int c = 0; c < HID; ++c) a1[c] = sb[c];
    const float4* xr = reinterpret_cast<const float4*>(x + (size_t)row * NDIM);
    #pragma unroll 8
    for (int k4 = 0; k4 < NDIM / 4; ++k4) {
        float4 v = xr[k4];
        const float* w0 = &sW1[(k4 * 4 + 0) * HID];
        const float* w1 = &sW1[(k4 * 4 + 1) * HID];
        const float* w2 = &sW1[(k4 * 4 + 2) * HID];
        const float* w3 = &sW1[(k4 * 4 + 3) * HID];
        #pragma unroll
        for (int c = 0; c < HID; ++c)
            a1[c] += v.x * w0[c] + v.y * w1[c] + v.z * w2[c] + v.w * w3[c];
    }

    float a2[HID];
    #pragma unroll
    for (int c = 0; c < HID; ++c) a2[c] = sb[HID + c];
    #pragma unroll
    for (int k = 0; k < HID; ++k) {
        const float hk = a1[k];
        #pragma unroll
        for (int c = 0; c < HID; ++c) a2[c] += hk * sW2[k * HID + c];
    }

    float a3[HID];
    #pragma unroll
    for (int c = 0; c < HID; ++c) a3[c] = sb[2 * HID + c];
    #pragma unroll
    for (int k = 0; k < HID; ++k) {
        const float hk = a2[k];
        #pragma unroll
        for (int c = 0; c < HID; ++c) a3[c] += hk * sW3[k * HID + c];
    }

    ushort hb[HID], hs[HID];
    #pragma unroll
    for (int c = 0; c < HID; ++c) {
        hb[c] = f2bf(a3[c]);
        hs[c] = f2bf(a3[c] * 1.44269504088896f);   // * log2(e)
    }
    uint wb[8], ws[8];
    #pragma unroll
    for (int d = 0; d < 8; ++d) {
        wb[d] = (uint)hb[2 * d] | ((uint)hb[2 * d + 1] << 16);
        ws[d] = (uint)hs[2 * d] | ((uint)hs[2 * d + 1] << 16);
    }
    uint4* pb = reinterpret_cast<uint4*>(g_hb  + (size_t)row * HID);
    uint4* ps = reinterpret_cast<uint4*>(g_hbs + (size_t)row * HID);
    pb[0] = make_uint4(wb[0], wb[1], wb[2], wb[3]);
    pb[1] = make_uint4(wb[4], wb[5], wb[6], wb[7]);
    ps[0] = make_uint4(ws[0], ws[1], ws[2], ws[3]);
    ps[1] = make_uint4(ws[4], ws[5], ws[6], ws[7]);
    #pragma unroll
    for (int c = 0; c < HID; ++c) g_hbT[(size_t)c * NROWS + row] = hb[c];
}

// ---------------------------------------------------------------------------
// Kernel B: MFMA flash aggregation.
// Wave: 32 i-rows. Per 32-j step:
//   S^T[j][i] = mfma_32x32x16(A=Hs[j-rows], B=H[i-rows], 0)   (K=HID=16)
//   p = exp2(S>0 ? S : -200)  (16 f32/lane; lane holds i=lane&31, j per reg)
//   cvt_pk + permlane32_swap -> two K=16 bf16 A-frags of P[i][j]
//   acc = mfma(P1, HT[j..j+15], acc); acc = mfma(P2, HT[j+16..j+31], acc)
// Partials (32i x 16c + den) stored per j-chunk; merged in finalize.
// ---------------------------------------------------------------------------
__global__ __launch_bounds__(256) void agg_kernel()
{
    const int lane = threadIdx.x & 63;
    const int wv   = threadIdx.x >> 6;
    const int jl   = lane & 31;       // row-in-tile for frag loads / col of S^T
    const int kh   = lane >> 5;       // k-half selector
    const int i0   = blockIdx.x * 128 + wv * 32;
    const int q    = blockIdx.y;
    const int jbase = q * JSPAN;

    // i-side B frag (unscaled H rows i0..i0+31), loaded once
    const s16x8 bi = *reinterpret_cast<const s16x8*>(&g_hb[((size_t)(i0 + jl)) * HID + kh * 8]);
    // PV B-side column base (cols >=16 are don't-care; clamp for safe addresses)
    const ushort* tcol = &g_hbT[(size_t)(lane & 15) * NROWS];

    f32x16 acc, z;
    #pragma unroll
    for (int r = 0; r < 16; ++r) { acc[r] = 0.0f; z[r] = 0.0f; }
    float dsum = 0.0f;

    for (int js = 0; js < JSTEPS; ++js) {
        const int j0 = jbase + js * 32;

        const s16x8 aj = *reinterpret_cast<const s16x8*>(&g_hbs[((size_t)(j0 + jl)) * HID + kh * 8]);
        f32x16 S = __builtin_amdgcn_mfma_f32_32x32x16_bf16(aj, bi, z, 0, 0, 0);

        float p[16];
        #pragma unroll
        for (int r = 0; r < 16; ++r) {
            const float s  = S[r];
            const float sel = (s > 0.0f) ? s : -200.0f;   // exp2(-200)=0 => strict mask
            p[r] = EXP2(sel);
            dsum += p[r];
        }

        // ---- chunk 1: j0..j0+15 (C regs 0..7) ----
        uint qa, qb, qc, qd;
        asm("v_cvt_pk_bf16_f32 %0, %1, %2" : "=v"(qa) : "v"(p[0]), "v"(p[1]));
        asm("v_cvt_pk_bf16_f32 %0, %1, %2" : "=v"(qb) : "v"(p[2]), "v"(p[3]));
        asm("v_cvt_pk_bf16_f32 %0, %1, %2" : "=v"(qc) : "v"(p[4]), "v"(p[5]));
        asm("v_cvt_pk_bf16_f32 %0, %1, %2" : "=v"(qd) : "v"(p[6]), "v"(p[7]));
        asm volatile("v_permlane32_swap_b32 %0, %1" : "+v"(qa), "+v"(qc));
        asm volatile("v_permlane32_swap_b32 %0, %1" : "+v"(qb), "+v"(qd));
        union { uint u[4]; s16x8 v; } A1;
        A1.u[0] = qa; A1.u[1] = qb; A1.u[2] = qc; A1.u[3] = qd;

        // ---- chunk 2: j0+16..j0+31 (C regs 8..15) ----
        uint qe, qf, qg, qh;
        asm("v_cvt_pk_bf16_f32 %0, %1, %2" : "=v"(qe) : "v"(p[8]),  "v"(p[9]));
        asm("v_cvt_pk_bf16_f32 %0, %1, %2" : "=v"(qf) : "v"(p[10]), "v"(p[11]));
        asm("v_cvt_pk_bf16_f32 %0, %1, %2" : "=v"(qg) : "v"(p[12]), "v"(p[13]));
        asm("v_cvt_pk_bf16_f32 %0, %1, %2" : "=v"(qh) : "v"(p[14]), "v"(p[15]));
        asm volatile("v_permlane32_swap_b32 %0, %1" : "+v"(qe), "+v"(qg));
        asm volatile("v_permlane32_swap_b32 %0, %1" : "+v"(qf), "+v"(qh));
        union { uint u[4]; s16x8 v; } A2;
        A2.u[0] = qe; A2.u[1] = qf; A2.u[2] = qg; A2.u[3] = qh;

        const s16x8 b1 = *reinterpret_cast<const s16x8*>(&tcol[j0 + kh * 8]);
        const s16x8 b2 = *reinterpret_cast<const s16x8*>(&tcol[j0 + 16 + kh * 8]);

        acc = __builtin_amdgcn_mfma_f32_32x32x16_bf16(A1.v, b1, acc, 0, 0, 0);
        acc = __builtin_amdgcn_mfma_f32_32x32x16_bf16(A2.v, b2, acc, 0, 0, 0);
    }

    // denominator: lane and lane^32 share the same i = lane&31
    dsum += __shfl_xor(dsum, 32, 64);
    if (lane < 32) g_pden[(size_t)q * NROWS + i0 + lane] = dsum;

    // PV output tile: col c = lane&31 (c<16 valid), row i = (r&3)+8*(r>>2)+4*kh
    const int c = lane & 31;
    if (c < 16) {
        #pragma unroll
        for (int r = 0; r < 16; ++r) {
            const int il = (r & 3) + 8 * (r >> 2) + 4 * kh;
            g_pout[((size_t)q * NROWS + (i0 + il)) * 16 + c] = acc[r];
        }
    }
}

// ---------------------------------------------------------------------------
// Kernel C: merge partials; out = log_softmax(num/den). 16 lanes per row.
// ---------------------------------------------------------------------------
__global__ __launch_bounds__(256) void finalize_kernel(float* __restrict__ out)
{
    const int gid = blockIdx.x * 256 + threadIdx.x;
    const int row = gid >> 4;
    const int c   = gid & 15;
    if (row >= NROWS) return;

    float num = 0.0f, den = 0.0f;
    #pragma unroll
    for (int q = 0; q < NJC; ++q) {
        num += g_pout[((size_t)q * NROWS + row) * 16 + c];
        den += g_pden[(size_t)q * NROWS + row];
    }
    const float o = num / den;

    float m = o;
    #pragma unroll
    for (int mask = 1; mask < 16; mask <<= 1) m = fmaxf(m, __shfl_xor(m, mask, 16));
    float e = __expf(o - m), s = e;
    #pragma unroll
    for (int mask = 1; mask < 16; mask <<= 1) s += __shfl_xor(s, mask, 16);

    out[(size_t)row * HID + c] = o - m - __logf(s);
}

// ---------------------------------------------------------------------------
extern "C" void kernel_launch(void* const* d_in, const int* in_sizes, int n_in,
                              void* d_out, int out_size, void* d_ws, size_t ws_size,
                              hipStream_t stream) {
    const float* x  = (const float*)d_in[0];
    const float* W1 = (const float*)d_in[1];
    const float* b1 = (const float*)d_in[2];
    const float* W2 = (const float*)d_in[3];
    const float* b2 = (const float*)d_in[4];
    const float* W3 = (const float*)d_in[5];
    const float* b3 = (const float*)d_in[6];
    float* out = (float*)d_out;

    mlp_kernel<<<NROWS / 256, 256, 0, stream>>>(x, W1, b1, W2, b2, W3, b3);
    agg_kernel<<<dim3(NROWS / 128, NJC), 256, 0, stream>>>();
    finalize_kernel<<<(NROWS * 16) / 256, 256, 0, stream>>>(out);
}

// Round 5
// 124.872 us; speedup vs baseline: 3.3594x; 1.0821x over previous
//
#include <hip/hip_runtime.h>
#include <hip/hip_bf16.h>

#define NROWS 12288
#define NDIM  128
#define HID   16

#define NJC    16                // j-chunks (partials)
#define JSPAN  (NROWS / NJC)     // 768
#define JSTEPS (JSPAN / 32)      // 24

typedef float f32x16 __attribute__((ext_vector_type(16)));
typedef short s16x8  __attribute__((ext_vector_type(8)));

// Module-level scratch (BSS): fully rewritten every call; no d_ws dependence.
__device__ __align__(16) ushort g_hb [NROWS * HID];        // bf16 H
__device__ __align__(16) ushort g_hbs[NROWS * HID];        // bf16 (H * log2e)  (QK^T j-side)
__device__ __align__(16) ushort g_hbT[17 * NROWS];         // bf16 H^T, row 16 = ones (denominator)
__device__ float g_pout[(size_t)NJC * NROWS * 17];         // PV partials: 16 num + 1 den per row

__device__ __forceinline__ ushort f2bf(float f) {          // RNE f32->bf16
    union { float f; unsigned u; } v; v.f = f;
    unsigned r = v.u + 0x7fffu + ((v.u >> 16) & 1u);
    return (ushort)(r >> 16);
}

__device__ __forceinline__ float fast_exp2(float x) {
#if __has_builtin(__builtin_amdgcn_exp2f)
    return __builtin_amdgcn_exp2f(x);
#else
    float r; asm("v_exp_f32 %0, %1" : "=v"(r) : "v"(x)); return r;
#endif
}

// ---------------------------------------------------------------------------
// Kernel A: MLP -> bf16 H, bf16 H*log2e, bf16 H^T (+ ones row).
// 64-thread blocks: 192 blocks to spread across CUs (was 48).
// ---------------------------------------------------------------------------
__global__ __launch_bounds__(64) void mlp_kernel(
    const float* __restrict__ x,
    const float* __restrict__ W1, const float* __restrict__ b1,
    const float* __restrict__ W2, const float* __restrict__ b2,
    const float* __restrict__ W3, const float* __restrict__ b3)
{
    __shared__ float sW1[NDIM * HID];
    __shared__ float sW2[HID * HID];
    __shared__ float sW3[HID * HID];
    __shared__ float sb[3 * HID];

    const int t = threadIdx.x;
    for (int i = t; i < NDIM * HID; i += 64) sW1[i] = W1[i];
    for (int i = t; i < HID * HID; i += 64) { sW2[i] = W2[i]; sW3[i] = W3[i]; }
    if (t < HID) { sb[t] = b1[t]; sb[HID + t] = b2[t]; sb[2 * HID + t] = b3[t]; }
    __syncthreads();

    const int row = blockIdx.x * 64 + t;
    if (row >= NROWS) return;

    float a1[HID];
    #pragma unroll
    for (int c = 0; c < HID; ++c) a1[c] = sb[c];
    const float4* xr = reinterpret_cast<const float4*>(x + (size_t)row * NDIM);
    #pragma unroll 8
    for (int k4 = 0; k4 < NDIM / 4; ++k4) {
        float4 v = xr[k4];
        const float* w0 = &sW1[(k4 * 4 + 0) * HID];
        const float* w1 = &sW1[(k4 * 4 + 1) * HID];
        const float* w2 = &sW1[(k4 * 4 + 2) * HID];
        const float* w3 = &sW1[(k4 * 4 + 3) * HID];
        #pragma unroll
        for (int c = 0; c < HID; ++c)
            a1[c] += v.x * w0[c] + v.y * w1[c] + v.z * w2[c] + v.w * w3[c];
    }

    float a2[HID];
    #pragma unroll
    for (int c = 0; c < HID; ++c) a2[c] = sb[HID + c];
    #pragma unroll
    for (int k = 0; k < HID; ++k) {
        const float hk = a1[k];
        #pragma unroll
        for (int c = 0; c < HID; ++c) a2[c] += hk * sW2[k * HID + c];
    }

    float a3[HID];
    #pragma unroll
    for (int c = 0; c < HID; ++c) a3[c] = sb[2 * HID + c];
    #pragma unroll
    for (int k = 0; k < HID; ++k) {
        const float hk = a2[k];
        #pragma unroll
        for (int c = 0; c < HID; ++c) a3[c] += hk * sW3[k * HID + c];
    }

    ushort hb[HID], hs[HID];
    #pragma unroll
    for (int c = 0; c < HID; ++c) {
        hb[c] = f2bf(a3[c]);
        hs[c] = f2bf(a3[c] * 1.44269504088896f);   // * log2(e)
    }
    uint wb[8], ws[8];
    #pragma unroll
    for (int d = 0; d < 8; ++d) {
        wb[d] = (uint)hb[2 * d] | ((uint)hb[2 * d + 1] << 16);
        ws[d] = (uint)hs[2 * d] | ((uint)hs[2 * d + 1] << 16);
    }
    uint4* pb = reinterpret_cast<uint4*>(g_hb  + (size_t)row * HID);
    uint4* ps = reinterpret_cast<uint4*>(g_hbs + (size_t)row * HID);
    pb[0] = make_uint4(wb[0], wb[1], wb[2], wb[3]);
    pb[1] = make_uint4(wb[4], wb[5], wb[6], wb[7]);
    ps[0] = make_uint4(ws[0], ws[1], ws[2], ws[3]);
    ps[1] = make_uint4(ws[4], ws[5], ws[6], ws[7]);
    #pragma unroll
    for (int c = 0; c < HID; ++c) g_hbT[(size_t)c * NROWS + row] = hb[c];
    g_hbT[(size_t)16 * NROWS + row] = 0x3F80;      // bf16(1.0): denominator column
}

// ---------------------------------------------------------------------------
// Kernel B: MFMA flash aggregation.
// Wave: 32 i-rows. Per 32-j step:
//   S^T[j][i] = mfma_32x32x16(A=Hs[j-rows], B=H[i-rows], 0)   (K=HID=16)
//   p = exp2(S>0 ? S : -200)  (16 f32/lane)
//   cvt_pk + permlane32_swap -> two K=16 bf16 A-frags of P[i][j]
//   acc = mfma(P1, HT[j..j+15], acc); acc = mfma(P2, HT[j+16..j+31], acc)
// B-side col 16 is all-ones => acc col 16 = sum_j p = denominator (free).
// Partials (32i x 17) stored per j-chunk; merged in finalize.
// ---------------------------------------------------------------------------
__global__ __launch_bounds__(256) void agg_kernel()
{
    const int lane = threadIdx.x & 63;
    const int wv   = threadIdx.x >> 6;
    const int jl   = lane & 31;       // row-in-tile for frag loads
    const int kh   = lane >> 5;       // k-half selector
    const int i0   = blockIdx.x * 128 + wv * 32;
    const int q    = blockIdx.y;
    const int jbase = q * JSPAN;

    // i-side B frag (unscaled H rows i0..i0+31), loaded once
    const s16x8 bi = *reinterpret_cast<const s16x8*>(&g_hb[((size_t)(i0 + jl)) * HID + kh * 8]);
    // PV B-side column base; cols >16 clamp to the ones-column (unused output)
    const int ccol = lane & 31;
    const ushort* tcol = &g_hbT[(size_t)(ccol < 16 ? ccol : 16) * NROWS];

    f32x16 acc, z;
    #pragma unroll
    for (int r = 0; r < 16; ++r) { acc[r] = 0.0f; z[r] = 0.0f; }

    for (int js = 0; js < JSTEPS; ++js) {
        const int j0 = jbase + js * 32;

        const s16x8 aj = *reinterpret_cast<const s16x8*>(&g_hbs[((size_t)(j0 + jl)) * HID + kh * 8]);
        f32x16 S = __builtin_amdgcn_mfma_f32_32x32x16_bf16(aj, bi, z, 0, 0, 0);

        float p[16];
        #pragma unroll
        for (int r = 0; r < 16; ++r) {
            const float s   = S[r];
            const float sel = (s > 0.0f) ? s : -200.0f;   // exp2(-200)=0 => strict mask
            p[r] = fast_exp2(sel);
        }

        // ---- chunk 1: j0..j0+15 (C regs 0..7) ----
        uint qa, qb, qc, qd;
        asm("v_cvt_pk_bf16_f32 %0, %1, %2" : "=v"(qa) : "v"(p[0]), "v"(p[1]));
        asm("v_cvt_pk_bf16_f32 %0, %1, %2" : "=v"(qb) : "v"(p[2]), "v"(p[3]));
        asm("v_cvt_pk_bf16_f32 %0, %1, %2" : "=v"(qc) : "v"(p[4]), "v"(p[5]));
        asm("v_cvt_pk_bf16_f32 %0, %1, %2" : "=v"(qd) : "v"(p[6]), "v"(p[7]));
        asm("v_permlane32_swap_b32 %0, %1" : "+v"(qa), "+v"(qc));
        asm("v_permlane32_swap_b32 %0, %1" : "+v"(qb), "+v"(qd));
        union { uint u[4]; s16x8 v; } A1;
        A1.u[0] = qa; A1.u[1] = qb; A1.u[2] = qc; A1.u[3] = qd;

        // ---- chunk 2: j0+16..j0+31 (C regs 8..15) ----
        uint qe, qf, qg, qh;
        asm("v_cvt_pk_bf16_f32 %0, %1, %2" : "=v"(qe) : "v"(p[8]),  "v"(p[9]));
        asm("v_cvt_pk_bf16_f32 %0, %1, %2" : "=v"(qf) : "v"(p[10]), "v"(p[11]));
        asm("v_cvt_pk_bf16_f32 %0, %1, %2" : "=v"(qg) : "v"(p[12]), "v"(p[13]));
        asm("v_cvt_pk_bf16_f32 %0, %1, %2" : "=v"(qh) : "v"(p[14]), "v"(p[15]));
        asm("v_permlane32_swap_b32 %0, %1" : "+v"(qe), "+v"(qg));
        asm("v_permlane32_swap_b32 %0, %1" : "+v"(qf), "+v"(qh));
        union { uint u[4]; s16x8 v; } A2;
        A2.u[0] = qe; A2.u[1] = qf; A2.u[2] = qg; A2.u[3] = qh;

        const s16x8 b1 = *reinterpret_cast<const s16x8*>(&tcol[j0 + kh * 8]);
        const s16x8 b2 = *reinterpret_cast<const s16x8*>(&tcol[j0 + 16 + kh * 8]);

        acc = __builtin_amdgcn_mfma_f32_32x32x16_bf16(A1.v, b1, acc, 0, 0, 0);
        acc = __builtin_amdgcn_mfma_f32_32x32x16_bf16(A2.v, b2, acc, 0, 0, 0);
    }

    // PV output tile: col c = lane&31 (c<=16 valid incl. den), row i = (r&3)+8*(r>>2)+4*kh
    if (ccol < 17) {
        #pragma unroll
        for (int r = 0; r < 16; ++r) {
            const int il = (r & 3) + 8 * (r >> 2) + 4 * kh;
            g_pout[((size_t)q * NROWS + (i0 + il)) * 17 + ccol] = acc[r];
        }
    }
}

// ---------------------------------------------------------------------------
// Kernel C: merge partials; out = log_softmax(num/den). 16 lanes per row.
// ---------------------------------------------------------------------------
__global__ __launch_bounds__(256) void finalize_kernel(float* __restrict__ out)
{
    const int gid = blockIdx.x * 256 + threadIdx.x;
    const int row = gid >> 4;
    const int c   = gid & 15;
    if (row >= NROWS) return;

    float num = 0.0f, den = 0.0f;
    #pragma unroll
    for (int q = 0; q < NJC; ++q) {
        const size_t base = ((size_t)q * NROWS + row) * 17;
        num += g_pout[base + c];
        den += g_pout[base + 16];
    }
    const float o = num / den;

    float m = o;
    #pragma unroll
    for (int mask = 1; mask < 16; mask <<= 1) m = fmaxf(m, __shfl_xor(m, mask, 16));
    float e = __expf(o - m), s = e;
    #pragma unroll
    for (int mask = 1; mask < 16; mask <<= 1) s += __shfl_xor(s, mask, 16);

    out[(size_t)row * HID + c] = o - m - __logf(s);
}

// ---------------------------------------------------------------------------
extern "C" void kernel_launch(void* const* d_in, const int* in_sizes, int n_in,
                              void* d_out, int out_size, void* d_ws, size_t ws_size,
                              hipStream_t stream) {
    const float* x  = (const float*)d_in[0];
    const float* W1 = (const float*)d_in[1];
    const float* b1 = (const float*)d_in[2];
    const float* W2 = (const float*)d_in[3];
    const float* b2 = (const float*)d_in[4];
    const float* W3 = (const float*)d_in[5];
    const float* b3 = (const float*)d_in[6];
    float* out = (float*)d_out;

    mlp_kernel<<<NROWS / 64, 64, 0, stream>>>(x, W1, b1, W2, b2, W3, b3);
    agg_kernel<<<dim3(NROWS / 128, NJC), 256, 0, stream>>>();
    finalize_kernel<<<(NROWS * 16) / 256, 256, 0, stream>>>(out);
}

// Round 9
// 123.870 us; speedup vs baseline: 3.3866x; 1.0081x over previous
//
#include <hip/hip_runtime.h>
#include <hip/hip_bf16.h>

#define NROWS 12288
#define NDIM  128
#define HID   16

#define NJC    16                // j-chunks (partials)
#define JSPAN  (NROWS / NJC)     // 768
#define JSTEPS (JSPAN / 32)      // 24

typedef float f32x16 __attribute__((ext_vector_type(16)));
typedef short s16x8  __attribute__((ext_vector_type(8)));

// Module-level scratch (BSS): fully rewritten every call; no d_ws dependence.
__device__ __align__(16) ushort g_hb [NROWS * HID];        // bf16 H
__device__ __align__(16) ushort g_hbs[NROWS * HID];        // bf16 (H * log2e)  (QK^T j-side)
__device__ __align__(16) ushort g_hbT[17 * NROWS];         // bf16 H^T, row 16 = ones (denominator)
__device__ float g_pout[(size_t)NJC * NROWS * 17];         // PV partials: 16 num + 1 den per row

__device__ __forceinline__ ushort f2bf(float f) {          // RNE f32->bf16
    union { float f; unsigned u; } v; v.f = f;
    unsigned r = v.u + 0x7fffu + ((v.u >> 16) & 1u);
    return (ushort)(r >> 16);
}

__device__ __forceinline__ float fast_exp2(float x) {
#if __has_builtin(__builtin_amdgcn_exp2f)
    return __builtin_amdgcn_exp2f(x);
#else
    float r; asm volatile("v_exp_f32 %0, %1" : "=v"(r) : "v"(x)); return r;
#endif
}

// ---------------------------------------------------------------------------
// Kernel A: MLP -> bf16 H, bf16 H*log2e, bf16 H^T (+ ones row).
// Round-5 version verbatim (known good).
// ---------------------------------------------------------------------------
__global__ __launch_bounds__(64) void mlp_kernel(
    const float* __restrict__ x,
    const float* __restrict__ W1, const float* __restrict__ b1,
    const float* __restrict__ W2, const float* __restrict__ b2,
    const float* __restrict__ W3, const float* __restrict__ b3)
{
    __shared__ float sW1[NDIM * HID];
    __shared__ float sW2[HID * HID];
    __shared__ float sW3[HID * HID];
    __shared__ float sb[3 * HID];

    const int t = threadIdx.x;
    for (int i = t; i < NDIM * HID; i += 64) sW1[i] = W1[i];
    for (int i = t; i < HID * HID; i += 64) { sW2[i] = W2[i]; sW3[i] = W3[i]; }
    if (t < HID) { sb[t] = b1[t]; sb[HID + t] = b2[t]; sb[2 * HID + t] = b3[t]; }
    __syncthreads();

    const int row = blockIdx.x * 64 + t;
    if (row >= NROWS) return;

    float a1[HID];
    #pragma unroll
    for (int c = 0; c < HID; ++c) a1[c] = sb[c];
    const float4* xr = reinterpret_cast<const float4*>(x + (size_t)row * NDIM);
    #pragma unroll 8
    for (int k4 = 0; k4 < NDIM / 4; ++k4) {
        float4 v = xr[k4];
        const float* w0 = &sW1[(k4 * 4 + 0) * HID];
        const float* w1 = &sW1[(k4 * 4 + 1) * HID];
        const float* w2 = &sW1[(k4 * 4 + 2) * HID];
        const float* w3 = &sW1[(k4 * 4 + 3) * HID];
        #pragma unroll
        for (int c = 0; c < HID; ++c)
            a1[c] += v.x * w0[c] + v.y * w1[c] + v.z * w2[c] + v.w * w3[c];
    }

    float a2[HID];
    #pragma unroll
    for (int c = 0; c < HID; ++c) a2[c] = sb[HID + c];
    #pragma unroll
    for (int k = 0; k < HID; ++k) {
        const float hk = a1[k];
        #pragma unroll
        for (int c = 0; c < HID; ++c) a2[c] += hk * sW2[k * HID + c];
    }

    float a3[HID];
    #pragma unroll
    for (int c = 0; c < HID; ++c) a3[c] = sb[2 * HID + c];
    #pragma unroll
    for (int k = 0; k < HID; ++k) {
        const float hk = a2[k];
        #pragma unroll
        for (int c = 0; c < HID; ++c) a3[c] += hk * sW3[k * HID + c];
    }

    ushort hb[HID], hs[HID];
    #pragma unroll
    for (int c = 0; c < HID; ++c) {
        hb[c] = f2bf(a3[c]);
        hs[c] = f2bf(a3[c] * 1.44269504088896f);   // * log2(e)
    }
    uint wb[8], ws[8];
    #pragma unroll
    for (int d = 0; d < 8; ++d) {
        wb[d] = (uint)hb[2 * d] | ((uint)hb[2 * d + 1] << 16);
        ws[d] = (uint)hs[2 * d] | ((uint)hs[2 * d + 1] << 16);
    }
    uint4* pb = reinterpret_cast<uint4*>(g_hb  + (size_t)row * HID);
    uint4* ps = reinterpret_cast<uint4*>(g_hbs + (size_t)row * HID);
    pb[0] = make_uint4(wb[0], wb[1], wb[2], wb[3]);
    pb[1] = make_uint4(wb[4], wb[5], wb[6], wb[7]);
    ps[0] = make_uint4(ws[0], ws[1], ws[2], ws[3]);
    ps[1] = make_uint4(ws[4], ws[5], ws[6], ws[7]);
    #pragma unroll
    for (int c = 0; c < HID; ++c) g_hbT[(size_t)c * NROWS + row] = hb[c];
    g_hbT[(size_t)16 * NROWS + row] = 0x3F80;      // bf16(1.0): denominator column
}

// ---------------------------------------------------------------------------
// Kernel B: MFMA flash aggregation. Round-5 source byte-exact EXCEPT all
// inline asm is now `asm volatile`.
// FORENSIC NOTE (r6/r7/r8 failures, absmax ~0.4): r7 failed with a body
// line-identical to r5's (geometry-only change); r8 failed with r5 geometry
// (order-only change); r4 (volatile permlane) and r5 passed. Non-volatile
// asm with "+v" read-write outputs is context-fragile (rematerialization /
// duplication of a swap breaks it: swap twice = identity). NEVER remove
// volatile from these; NEVER add a min-waves arg to launch_bounds here.
// Wave: 32 i-rows. Per 32-j step:
//   S^T[j][i] = mfma_32x32x16(A=Hs[j-rows], B=H[i-rows], 0)   (K=HID=16)
//   p = exp2(S>0 ? S : -200)  (16 f32/lane)
//   cvt_pk + permlane32_swap -> two K=16 bf16 A-frags of P[i][j]
//   acc = mfma(P1, HT[j..j+15], acc); acc = mfma(P2, HT[j+16..j+31], acc)
// B-side col 16 is all-ones => acc col 16 = sum_j p = denominator (free).
// ---------------------------------------------------------------------------
__global__ __launch_bounds__(256) void agg_kernel()
{
    const int lane = threadIdx.x & 63;
    const int wv   = threadIdx.x >> 6;
    const int jl   = lane & 31;       // row-in-tile for frag loads
    const int kh   = lane >> 5;       // k-half selector
    const int i0   = blockIdx.x * 128 + wv * 32;
    const int q    = blockIdx.y;
    const int jbase = q * JSPAN;

    // i-side B frag (unscaled H rows i0..i0+31), loaded once
    const s16x8 bi = *reinterpret_cast<const s16x8*>(&g_hb[((size_t)(i0 + jl)) * HID + kh * 8]);
    // PV B-side column base; cols >16 clamp to the ones-column (unused output)
    const int ccol = lane & 31;
    const ushort* tcol = &g_hbT[(size_t)(ccol < 16 ? ccol : 16) * NROWS];

    f32x16 acc, z;
    #pragma unroll
    for (int r = 0; r < 16; ++r) { acc[r] = 0.0f; z[r] = 0.0f; }

    for (int js = 0; js < JSTEPS; ++js) {
        const int j0 = jbase + js * 32;

        const s16x8 aj = *reinterpret_cast<const s16x8*>(&g_hbs[((size_t)(j0 + jl)) * HID + kh * 8]);
        f32x16 S = __builtin_amdgcn_mfma_f32_32x32x16_bf16(aj, bi, z, 0, 0, 0);

        float p[16];
        #pragma unroll
        for (int r = 0; r < 16; ++r) {
            const float s   = S[r];
            const float sel = (s > 0.0f) ? s : -200.0f;   // exp2(-200)=0 => strict mask
            p[r] = fast_exp2(sel);
        }

        // ---- chunk 1: j0..j0+15 (C regs 0..7) ----
        uint qa, qb, qc, qd;
        asm volatile("v_cvt_pk_bf16_f32 %0, %1, %2" : "=v"(qa) : "v"(p[0]), "v"(p[1]));
        asm volatile("v_cvt_pk_bf16_f32 %0, %1, %2" : "=v"(qb) : "v"(p[2]), "v"(p[3]));
        asm volatile("v_cvt_pk_bf16_f32 %0, %1, %2" : "=v"(qc) : "v"(p[4]), "v"(p[5]));
        asm volatile("v_cvt_pk_bf16_f32 %0, %1, %2" : "=v"(qd) : "v"(p[6]), "v"(p[7]));
        asm volatile("v_permlane32_swap_b32 %0, %1" : "+v"(qa), "+v"(qc));
        asm volatile("v_permlane32_swap_b32 %0, %1" : "+v"(qb), "+v"(qd));
        union { uint u[4]; s16x8 v; } A1;
        A1.u[0] = qa; A1.u[1] = qb; A1.u[2] = qc; A1.u[3] = qd;

        // ---- chunk 2: j0+16..j0+31 (C regs 8..15) ----
        uint qe, qf, qg, qh;
        asm volatile("v_cvt_pk_bf16_f32 %0, %1, %2" : "=v"(qe) : "v"(p[8]),  "v"(p[9]));
        asm volatile("v_cvt_pk_bf16_f32 %0, %1, %2" : "=v"(qf) : "v"(p[10]), "v"(p[11]));
        asm volatile("v_cvt_pk_bf16_f32 %0, %1, %2" : "=v"(qg) : "v"(p[12]), "v"(p[13]));
        asm volatile("v_cvt_pk_bf16_f32 %0, %1, %2" : "=v"(qh) : "v"(p[14]), "v"(p[15]));
        asm volatile("v_permlane32_swap_b32 %0, %1" : "+v"(qe), "+v"(qg));
        asm volatile("v_permlane32_swap_b32 %0, %1" : "+v"(qf), "+v"(qh));
        union { uint u[4]; s16x8 v; } A2;
        A2.u[0] = qe; A2.u[1] = qf; A2.u[2] = qg; A2.u[3] = qh;

        const s16x8 b1 = *reinterpret_cast<const s16x8*>(&tcol[j0 + kh * 8]);
        const s16x8 b2 = *reinterpret_cast<const s16x8*>(&tcol[j0 + 16 + kh * 8]);

        acc = __builtin_amdgcn_mfma_f32_32x32x16_bf16(A1.v, b1, acc, 0, 0, 0);
        acc = __builtin_amdgcn_mfma_f32_32x32x16_bf16(A2.v, b2, acc, 0, 0, 0);
    }

    // PV output tile: col c = lane&31 (c<=16 valid incl. den), row i = (r&3)+8*(r>>2)+4*kh
    if (ccol < 17) {
        #pragma unroll
        for (int r = 0; r < 16; ++r) {
            const int il = (r & 3) + 8 * (r >> 2) + 4 * kh;
            g_pout[((size_t)q * NROWS + (i0 + il)) * 17 + ccol] = acc[r];
        }
    }
}

// ---------------------------------------------------------------------------
// Kernel C: merge partials; out = log_softmax(num/den). 16 lanes per row.
// ---------------------------------------------------------------------------
__global__ __launch_bounds__(256) void finalize_kernel(float* __restrict__ out)
{
    const int gid = blockIdx.x * 256 + threadIdx.x;
    const int row = gid >> 4;
    const int c   = gid & 15;
    if (row >= NROWS) return;

    float num = 0.0f, den = 0.0f;
    #pragma unroll
    for (int q = 0; q < NJC; ++q) {
        const size_t base = ((size_t)q * NROWS + row) * 17;
        num += g_pout[base + c];
        den += g_pout[base + 16];
    }
    const float o = num / den;

    float m = o;
    #pragma unroll
    for (int mask = 1; mask < 16; mask <<= 1) m = fmaxf(m, __shfl_xor(m, mask, 16));
    float e = __expf(o - m), s = e;
    #pragma unroll
    for (int mask = 1; mask < 16; mask <<= 1) s += __shfl_xor(s, mask, 16);

    out[(size_t)row * HID + c] = o - m - __logf(s);
}

// ---------------------------------------------------------------------------
extern "C" void kernel_launch(void* const* d_in, const int* in_sizes, int n_in,
                              void* d_out, int out_size, void* d_ws, size_t ws_size,
                              hipStream_t stream) {
    const float* x  = (const float*)d_in[0];
    const float* W1 = (const float*)d_in[1];
    const float* b1 = (const float*)d_in[2];
    const float* W2 = (const float*)d_in[3];
    const float* b2 = (const float*)d_in[4];
    const float* W3 = (const float*)d_in[5];
    const float* b3 = (const float*)d_in[6];
    float* out = (float*)d_out;

    mlp_kernel<<<NROWS / 64, 64, 0, stream>>>(x, W1, b1, W2, b2, W3, b3);
    agg_kernel<<<dim3(NROWS / 128, NJC), 256, 0, stream>>>();
    finalize_kernel<<<(NROWS * 16) / 256, 256, 0, stream>>>(out);
}